// Round 2
// baseline (187.944 us; speedup 1.0000x reference)
//
#include <hip/hip_runtime.h>
#include <hip/hip_bf16.h>
#include <cstdint>

#define NROWS 8192
#define DDIM  256
#define THR   0.95f
#define EPSN  1e-8f
#define IMAX  0x7FFFFFFF

typedef unsigned short u16;

__device__ __forceinline__ float b2f(u16 u) {
    union { float f; unsigned int i; } v; v.i = ((unsigned int)u) << 16; return v.f;
}
__device__ __forceinline__ u16 f2b(float f) {
    union { float f; unsigned int i; } v; v.f = f;
    if ((v.i & 0x7F800000u) == 0x7F800000u) {
        return (u16)((v.i >> 16) | ((v.i & 0xFFFFu) ? 0x40 : 0));
    }
    unsigned int r = v.i + 0x7FFFu + ((v.i >> 16) & 1u);
    return (u16)(r >> 16);
}

// --- K1: row-normalize (fp32 norm, clamp eps), store normalized rows as bf16 ---
__global__ __launch_bounds__(256) void k_normalize(const float* __restrict__ kin,
                                                   u16* __restrict__ anorm) {
    const int row = blockIdx.x;
    const int t = threadIdx.x;            // 0..255, one element each
    const float v = kin[(size_t)row * DDIM + t];
    float s = v * v;
    for (int o = 32; o >= 1; o >>= 1) s += __shfl_xor(s, o);
    __shared__ float ws4[4];
    const int w = t >> 6, l = t & 63;
    if (l == 0) ws4[w] = s;
    __syncthreads();
    const float tot = ws4[0] + ws4[1] + ws4[2] + ws4[3];
    const float r = 1.0f / fmaxf(sqrtf(tot), EPSN);
    anorm[(size_t)row * DDIM + t] = f2b(v * r);
}

// --- K2: per column j, find first & second same-category hit rows i<=j ---
__global__ __launch_bounds__(256) void k_hits(const u16* __restrict__ anorm,
                                              const int* __restrict__ cat,
                                              int* __restrict__ hit1,
                                              int* __restrict__ hit2,
                                              int* __restrict__ mergeCnt,
                                              int* __restrict__ mergeList) {
    const int j = blockIdx.x;
    const int t = threadIdx.x, w = t >> 6, l = t & 63;
    const int cj = cat[j];

    // x_j fragment: lane l holds elems 4l..4l+3 (replicated across the 4 waves)
    float x0, x1, x2, x3;
    {
        const u16* xp = anorm + (size_t)j * DDIM + 4 * l;
        x0 = b2f(xp[0]); x1 = b2f(xp[1]); x2 = b2f(xp[2]); x3 = b2f(xp[3]);
    }

    __shared__ int wh1[4], wh2[4];
    __shared__ int H1s, H2s;
    if (t == 0) { H1s = IMAX; H2s = IMAX; }
    __syncthreads();

    for (int base = 0; base <= j; base += 256) {
        const int i = base + t;
        const bool match = (i <= j) && (cat[i] == cj);
        unsigned long long m = __ballot(match);
        int h1 = IMAX, h2 = IMAX;
        while (m) {
            const int b = __ffsll(m) - 1;
            m &= m - 1;
            const int ic = base + (w << 6) + b;
            const u16* ap = anorm + (size_t)ic * DDIM + 4 * l;
            float s = b2f(ap[0]) * x0 + b2f(ap[1]) * x1 +
                      b2f(ap[2]) * x2 + b2f(ap[3]) * x3;
            for (int o = 32; o >= 1; o >>= 1) s += __shfl_xor(s, o);
            if (s >= THR) {
                if (h1 == IMAX) h1 = ic;
                else { h2 = ic; break; }   // bits ascend -> two smallest in wave
            }
        }
        if (l == 0) { wh1[w] = h1; wh2[w] = h2; }
        __syncthreads();
        if (t == 0) {
            int a = H1s, bb = H2s;
            for (int q = 0; q < 4; q++) {
                int c1 = wh1[q], c2 = wh2[q];
                if (c1 < a) { bb = a; a = c1; } else if (c1 < bb) bb = c1;
                if (c2 < a) { bb = a; a = c2; } else if (c2 < bb) bb = c2;
            }
            H1s = a; H2s = bb;
        }
        __syncthreads();
        if (H2s != IMAX) break;   // two hits found; chunks ascend -> final
    }

    if (t == 0) {
        hit1[j] = H1s;
        hit2[j] = H2s;
        if (H1s != IMAX && H1s != j) {      // off-diagonal first hit -> merge candidate
            const int p = atomicAdd(mergeCnt, 1);
            mergeList[p] = j;
        }
    }
}

// --- K3: outputs (all float32): fused mean | cats | scores | keep ---
__global__ __launch_bounds__(256) void k_out(const float* __restrict__ kin,
                                             const int* __restrict__ cat,
                                             const float* __restrict__ sc,
                                             const int* __restrict__ hit1,
                                             const int* __restrict__ hit2,
                                             const int* __restrict__ mergeCnt,
                                             const int* __restrict__ mergeList,
                                             float* __restrict__ out) {
    const int i = blockIdx.x;
    const int t = threadIdx.x;
    const bool keep = (hit2[i] == IMAX);   // fewer than 2 hits in column i

    float* fused = out;                          // N*D
    float* cats  = out + (size_t)NROWS * DDIM;   // N
    float* scso  = cats + NROWS;                 // N
    float* keepo = scso + NROWS;                 // N

    float acc = 0.0f;
    int cnt = 0;
    if (keep) {
        if (hit1[i] == i) { acc = kin[(size_t)i * DDIM + t]; cnt = 1; }
        const int mc = *mergeCnt;
        for (int q = 0; q < mc; q++) {
            const int j = mergeList[q];
            if (hit1[j] == i) { acc += kin[(size_t)j * DDIM + t]; cnt++; }
        }
    }
    fused[(size_t)i * DDIM + t] = keep ? acc / (float)(cnt > 0 ? cnt : 1) : 0.0f;

    if (t == 0) {
        cats[i]  = keep ? (float)cat[i] : -1.0f;
        scso[i]  = keep ? sc[i] : 0.0f;
        keepo[i] = keep ? 1.0f : 0.0f;
    }
}

extern "C" void kernel_launch(void* const* d_in, const int* in_sizes, int n_in,
                              void* d_out, int out_size, void* d_ws, size_t ws_size,
                              hipStream_t stream) {
    (void)in_sizes; (void)n_in; (void)out_size; (void)ws_size;
    const float* kin = (const float*)d_in[0];   // kernels, fp32 [N*D]
    const int*   cat = (const int*)d_in[1];     // categories, int32 [N]
    const float* sc  = (const float*)d_in[2];   // scores, fp32 [N]
    float* out = (float*)d_out;                 // fp32, concat: fused|cats|scores|keep

    char* ws = (char*)d_ws;
    u16* anorm     = (u16*)ws;                                  // 4 MB (bf16 normalized rows)
    int* hit1      = (int*)(ws + (size_t)NROWS * DDIM * 2);     // 32 KB
    int* hit2      = hit1 + NROWS;                              // 32 KB
    int* mergeCnt  = hit2 + NROWS;                              // counter
    int* mergeList = mergeCnt + 16;                             // 32 KB

    hipMemsetAsync(mergeCnt, 0, sizeof(int), stream);
    k_normalize<<<NROWS, 256, 0, stream>>>(kin, anorm);
    k_hits<<<NROWS, 256, 0, stream>>>(anorm, cat, hit1, hit2, mergeCnt, mergeList);
    k_out<<<NROWS, 256, 0, stream>>>(kin, cat, sc, hit1, hit2, mergeCnt, mergeList, out);
}

// Round 3
// 124.621 us; speedup vs baseline: 1.5081x; 1.5081x over previous
//
#include <hip/hip_runtime.h>
#include <cstdint>

#define NROWS 8192
#define DDIM  256
#define THR   0.95f
#define EPSN  1e-8f
#define IMAX  0x7FFFFFFF
#define NCAT  80
#define SCHUNKS 128
#define RPC   (NROWS / SCHUNKS)   // 64 rows per sorter-thread chunk

typedef unsigned short u16;

__device__ __forceinline__ u16 f2b(float f) {
    union { float f; unsigned int i; } v; v.f = f;
    if ((v.i & 0x7F800000u) == 0x7F800000u) {
        return (u16)((v.i >> 16) | ((v.i & 0xFFFFu) ? 0x40 : 0));
    }
    unsigned int r = v.i + 0x7FFFu + ((v.i >> 16) & 1u);
    return (u16)(r >> 16);
}
__device__ __forceinline__ void unp(unsigned int u, float& a, float& b) {
    union { float f; unsigned int i; } x, y;
    x.i = u << 16; y.i = u & 0xFFFF0000u; a = x.f; b = y.f;
}

// ---- Dispatch 1: blocks 0..2047 normalize (1 row/wave); block 2048 = counting sort ----
__global__ __launch_bounds__(256) void k_norm_sort(const float* __restrict__ kin,
                                                   const int* __restrict__ cat,
                                                   u16* __restrict__ anorm,
                                                   int* __restrict__ sortedRows,
                                                   int* __restrict__ posOf,
                                                   int* __restrict__ catBase,
                                                   int* __restrict__ mergeCnt) {
    const int t = threadIdx.x;
    if (blockIdx.x < NROWS / 4) {
        const int w = t >> 6, l = t & 63;
        const int row = (blockIdx.x << 2) + w;
        const float4 v = ((const float4*)(kin + (size_t)row * DDIM))[l];
        float s = v.x * v.x + v.y * v.y + v.z * v.z + v.w * v.w;
        for (int o = 32; o >= 1; o >>= 1) s += __shfl_xor(s, o);
        const float rn = 1.0f / fmaxf(sqrtf(s), EPSN);
        ushort4 o4;
        o4.x = f2b(v.x * rn); o4.y = f2b(v.y * rn);
        o4.z = f2b(v.z * rn); o4.w = f2b(v.w * rn);
        ((ushort4*)(anorm + (size_t)row * DDIM))[l] = o4;
        return;
    }
    // ---- sorter block: stable counting sort of rows by category ----
    __shared__ u16 h[NCAT][SCHUNKS];       // 20 KB
    __shared__ int tot[NCAT];
    __shared__ int base[NCAT + 1];
    for (int idx = t; idx < NCAT * SCHUNKS; idx += 256) ((u16*)h)[idx] = 0;
    __syncthreads();
    if (t < SCHUNKS) {
        const int r0 = t * RPC;
        for (int k = 0; k < RPC; k++) h[cat[r0 + k]][t]++;
    }
    __syncthreads();
    if (t < NCAT) {
        int s = 0;
        for (int q = 0; q < SCHUNKS; q++) s += h[t][q];
        tot[t] = s;
    }
    __syncthreads();
    if (t == 0) {
        int run = 0;
        for (int c = 0; c < NCAT; c++) { base[c] = run; run += tot[c]; }
        base[NCAT] = run;
        *mergeCnt = 0;
    }
    __syncthreads();
    if (t <= NCAT) catBase[t] = base[t];
    if (t < NCAT) {                         // per-chunk exclusive offsets within category
        int run = 0;
        for (int q = 0; q < SCHUNKS; q++) { const u16 v = h[t][q]; h[t][q] = (u16)run; run += v; }
    }
    __syncthreads();
    if (t < SCHUNKS) {                      // stable scatter
        const int r0 = t * RPC;
        for (int k = 0; k < RPC; k++) {
            const int r = r0 + k, c = cat[r];
            const int rel = h[c][t]++;      // (c,t) cell owned by thread t — race-free
            sortedRows[base[c] + rel] = r;
            posOf[r] = rel;                 // # same-cat rows with index < r
        }
    }
}

// ---- Dispatch 2: one wave per column j — first/second same-cat hit with sim >= THR ----
#define UPD(r, s) do { if ((s) >= THR) { if (h1 == IMAX) h1 = (r); else if (h2 == IMAX) h2 = (r); } } while (0)

__device__ __forceinline__ float dot4(uint2 av, float x0, float x1, float x2, float x3) {
    float a0, a1, a2, a3;
    unp(av.x, a0, a1); unp(av.y, a2, a3);
    return a0 * x0 + a1 * x1 + a2 * x2 + a3 * x3;
}

__global__ __launch_bounds__(256) void k_hits2(const u16* __restrict__ anorm,
                                               const int* __restrict__ cat,
                                               const int* __restrict__ sortedRows,
                                               const int* __restrict__ posOf,
                                               const int* __restrict__ catBase,
                                               int* __restrict__ hit1,
                                               int* __restrict__ hit2,
                                               int* __restrict__ mergeCnt,
                                               int* __restrict__ mergeList) {
    const int t = threadIdx.x, l = t & 63;
    const int j = __builtin_amdgcn_readfirstlane((int)(blockIdx.x << 2) + (t >> 6));
    const int c = cat[j];
    const int npr = posOf[j];
    const int* lst = sortedRows + catBase[c];
    float x0, x1, x2, x3;
    {
        const uint2 xv = *((const uint2*)(anorm + (size_t)j * DDIM) + l);
        unp(xv.x, x0, x1); unp(xv.y, x2, x3);
    }
    int h1 = IMAX, h2 = IMAX;
    int q = 0;
    for (; q + 4 <= npr; q += 4) {
        const int r0 = lst[q], r1 = lst[q + 1], r2 = lst[q + 2], r3 = lst[q + 3];
        const uint2 a0 = *((const uint2*)(anorm + (size_t)r0 * DDIM) + l);
        const uint2 a1 = *((const uint2*)(anorm + (size_t)r1 * DDIM) + l);
        const uint2 a2 = *((const uint2*)(anorm + (size_t)r2 * DDIM) + l);
        const uint2 a3 = *((const uint2*)(anorm + (size_t)r3 * DDIM) + l);
        float s0 = dot4(a0, x0, x1, x2, x3);
        float s1 = dot4(a1, x0, x1, x2, x3);
        float s2 = dot4(a2, x0, x1, x2, x3);
        float s3 = dot4(a3, x0, x1, x2, x3);
        for (int o = 32; o >= 1; o >>= 1) {
            s0 += __shfl_xor(s0, o); s1 += __shfl_xor(s1, o);
            s2 += __shfl_xor(s2, o); s3 += __shfl_xor(s3, o);
        }
        UPD(r0, s0); UPD(r1, s1); UPD(r2, s2); UPD(r3, s3);
    }
    for (; q < npr; q++) {
        const int r = lst[q];
        const uint2 av = *((const uint2*)(anorm + (size_t)r * DDIM) + l);
        float s = dot4(av, x0, x1, x2, x3);
        for (int o = 32; o >= 1; o >>= 1) s += __shfl_xor(s, o);
        UPD(r, s);
    }
    // diagonal (row j) always hits; it is the largest candidate index
    if (h1 == IMAX) h1 = j; else if (h2 == IMAX) h2 = j;
    if (l == 0) {
        hit1[j] = h1; hit2[j] = h2;
        if (h1 != j) mergeList[atomicAdd(mergeCnt, 1)] = j;   // merged-away column
    }
}

// ---- Dispatch 3: outputs (fp32): fused | cats | scores | keep — 1 row/wave ----
__global__ __launch_bounds__(256) void k_out(const float* __restrict__ kin,
                                             const int* __restrict__ cat,
                                             const float* __restrict__ sc,
                                             const int* __restrict__ hit1,
                                             const int* __restrict__ hit2,
                                             const int* __restrict__ mergeCnt,
                                             const int* __restrict__ mergeList,
                                             float* __restrict__ out) {
    const int t = threadIdx.x, l = t & 63;
    const int i = __builtin_amdgcn_readfirstlane((int)(blockIdx.x << 2) + (t >> 6));
    const bool keep = (hit2[i] == IMAX);

    float* fused = out;                          // N*D
    float* cats  = out + (size_t)NROWS * DDIM;   // N
    float* scso  = cats + NROWS;                 // N
    float* keepo = scso + NROWS;                 // N

    float ax = 0.f, ay = 0.f, az = 0.f, aw = 0.f;
    if (keep) {
        // keep[i] => hit1[i] == i (diagonal is the sole first hit)
        const float4 v = ((const float4*)(kin + (size_t)i * DDIM))[l];
        ax = v.x; ay = v.y; az = v.z; aw = v.w;
        int cnt = 1;
        const int mc = *mergeCnt;
        for (int q = 0; q < mc; q++) {
            const int jr = mergeList[q];
            if (hit1[jr] == i) {
                const float4 b = ((const float4*)(kin + (size_t)jr * DDIM))[l];
                ax += b.x; ay += b.y; az += b.z; aw += b.w; cnt++;
            }
        }
        const float fc = (float)cnt;
        ax /= fc; ay /= fc; az /= fc; aw /= fc;
    }
    float4 o4; o4.x = ax; o4.y = ay; o4.z = az; o4.w = aw;
    ((float4*)(fused + (size_t)i * DDIM))[l] = o4;

    if (l == 0) {
        cats[i]  = keep ? (float)cat[i] : -1.0f;
        scso[i]  = keep ? sc[i] : 0.0f;
        keepo[i] = keep ? 1.0f : 0.0f;
    }
}

extern "C" void kernel_launch(void* const* d_in, const int* in_sizes, int n_in,
                              void* d_out, int out_size, void* d_ws, size_t ws_size,
                              hipStream_t stream) {
    (void)in_sizes; (void)n_in; (void)out_size; (void)ws_size;
    const float* kin = (const float*)d_in[0];   // kernels fp32 [N*D]
    const int*   cat = (const int*)d_in[1];     // categories int32 [N]
    const float* sc  = (const float*)d_in[2];   // scores fp32 [N]
    float* out = (float*)d_out;                 // fp32 concat: fused|cats|scores|keep

    char* ws = (char*)d_ws;
    u16* anorm      = (u16*)ws;                                   // 4 MB bf16 normalized rows
    int* hit1       = (int*)(ws + (size_t)NROWS * DDIM * 2);
    int* hit2       = hit1 + NROWS;
    int* sortedRows = hit2 + NROWS;
    int* posOf      = sortedRows + NROWS;
    int* catBase    = posOf + NROWS;            // 81 + pad
    int* mergeCnt   = catBase + 128;
    int* mergeList  = mergeCnt + 16;

    k_norm_sort<<<NROWS / 4 + 1, 256, 0, stream>>>(kin, cat, anorm, sortedRows,
                                                   posOf, catBase, mergeCnt);
    k_hits2<<<NROWS / 4, 256, 0, stream>>>(anorm, cat, sortedRows, posOf, catBase,
                                           hit1, hit2, mergeCnt, mergeList);
    k_out<<<NROWS / 4, 256, 0, stream>>>(kin, cat, sc, hit1, hit2,
                                         mergeCnt, mergeList, out);
}

// Round 4
// 94.940 us; speedup vs baseline: 1.9796x; 1.3126x over previous
//
#include <hip/hip_runtime.h>
#include <cstdint>

#define NROWS 8192
#define DDIM  256
#define THR   0.95f
#define EPSN  1e-8f
#define IMAX  0x7FFFFFFF
#define NCAT  80
#define MAXT  16   // max col-tiles per category (supports nc <= 256; mean 102, sd 10)

typedef unsigned short u16;
typedef short v8s __attribute__((ext_vector_type(8)));
typedef float v4f __attribute__((ext_vector_type(4)));

__device__ __forceinline__ u16 f2b(float f) {
    union { float f; unsigned int i; } v; v.f = f;
    if ((v.i & 0x7F800000u) == 0x7F800000u) {
        return (u16)((v.i >> 16) | ((v.i & 0xFFFFu) ? 0x40 : 0));
    }
    unsigned int r = v.i + 0x7FFFu + ((v.i >> 16) & 1u);
    return (u16)(r >> 16);
}

// ---- D1: blocks 0..2047 normalize (1 row/wave); block 2048 = parallel counting sort ----
__global__ __launch_bounds__(256) void k_norm_sort(const float* __restrict__ kin,
                                                   const int* __restrict__ cat,
                                                   u16* __restrict__ anorm,
                                                   int* __restrict__ sortedRows,
                                                   int* __restrict__ catBase,
                                                   int* __restrict__ mergeCnt) {
    const int t = threadIdx.x;
    if (blockIdx.x < NROWS / 4) {
        const int w = t >> 6, l = t & 63;
        const int row = (blockIdx.x << 2) + w;
        const float4 v = ((const float4*)(kin + (size_t)row * DDIM))[l];
        float s = v.x * v.x + v.y * v.y + v.z * v.z + v.w * v.w;
        for (int o = 32; o >= 1; o >>= 1) s += __shfl_xor(s, o);
        const float rn = 1.0f / fmaxf(sqrtf(s), EPSN);
        ushort4 o4;
        o4.x = f2b(v.x * rn); o4.y = f2b(v.y * rn);
        o4.z = f2b(v.z * rn); o4.w = f2b(v.w * rn);
        ((ushort4*)(anorm + (size_t)row * DDIM))[l] = o4;
        return;
    }
    // stable counting sort of rows by category, 256 chunks x 32 rows
    __shared__ u16 h[NCAT][256];       // 40 KB
    __shared__ int tot[NCAT];
    __shared__ int base[NCAT + 1];
    for (int i = t; i < NCAT * 256; i += 256) ((u16*)h)[i] = 0;
    __syncthreads();
    {
        const int r0 = t << 5;
        for (int k = 0; k < 32; ++k) h[cat[r0 + k]][t]++;
    }
    __syncthreads();
    if (t < NCAT) {
        int s = 0;
        for (int q = 0; q < 256; ++q) s += (int)h[t][q];
        tot[t] = s;
    }
    __syncthreads();
    if (t == 0) {
        int run = 0;
        for (int c = 0; c < NCAT; ++c) { base[c] = run; run += tot[c]; }
        base[NCAT] = run;
        *mergeCnt = 0;
    }
    __syncthreads();
    if (t <= NCAT) catBase[t] = base[t];
    if (t < NCAT) {                     // per-chunk exclusive offsets within category
        int run = 0;
        for (int q = 0; q < 256; ++q) { const int v = (int)h[t][q]; h[t][q] = (u16)run; run += v; }
    }
    __syncthreads();
    {
        const int r0 = t << 5;
        for (int k = 0; k < 32; ++k) {
            const int r = r0 + k, c = cat[r];
            const int rel = (int)h[c][t]++;       // cell (c,t) owned by thread t
            sortedRows[base[c] + rel] = r;        // ascending original index per category
        }
    }
}

// ---- D2: MFMA hit search. Block = (category, col-tile). S = A·A^T per category. ----
__global__ __launch_bounds__(256) void k_hits_cat(const u16* __restrict__ anorm,
                                                  const float* __restrict__ sc,
                                                  const int* __restrict__ sortedRows,
                                                  const int* __restrict__ catBase,
                                                  int* __restrict__ hit1,
                                                  int* __restrict__ hit2,
                                                  int* __restrict__ mergeCnt,
                                                  int* __restrict__ mergeList,
                                                  float* __restrict__ out) {
    const int c  = blockIdx.x >> 4;
    const int ct = blockIdx.x & 15;
    const int nbase = catBase[c];
    const int nc = catBase[c + 1] - nbase;
    const int ncT = (nc + 15) >> 4;
    if (ct >= ncT) return;
    const int* lst = sortedRows + nbase;

    __shared__ int colH1[16];
    const int t = threadIdx.x;
    if (t < 16) colH1[t] = IMAX;
    __syncthreads();

    const int wv = t >> 6, l = t & 63;
    const int lo16 = l & 15, quad = l >> 4;

    // B fragment: column-tile rows, n = lane&15, k = quad*8 + e  (8 bf16 = 16 B)
    const int qloc = (ct << 4) + lo16;
    const int gq = lst[qloc < nc ? qloc : nc - 1];
    const u16* qrow = anorm + ((size_t)gq << 8) + (quad << 3);
    v8s bfr[8];
#pragma unroll
    for (int kk = 0; kk < 8; ++kk) bfr[kk] = *(const v8s*)(qrow + (kk << 5));

    for (int rt = wv; rt <= ct; rt += 4) {
        const int ploc = (rt << 4) + lo16;
        const int gp = lst[ploc < nc ? ploc : nc - 1];
        const u16* prow = anorm + ((size_t)gp << 8) + (quad << 3);
        v4f acc = {0.f, 0.f, 0.f, 0.f};
#pragma unroll
        for (int kk = 0; kk < 8; ++kk) {
            const v8s af = *(const v8s*)(prow + (kk << 5));
            acc = __builtin_amdgcn_mfma_f32_16x16x32_bf16(af, bfr[kk], acc, 0, 0, 0);
        }
        // D layout: col n = lane&15 (-> qloc), row m = quad*4 + reg
#pragma unroll
        for (int reg = 0; reg < 4; ++reg) {
            const int p = (rt << 4) + (quad << 2) + reg;
            if (acc[reg] >= THR && p < qloc && qloc < nc) atomicMin(&colH1[lo16], p);
        }
    }
    __syncthreads();

    if (t < 16) {
        const int q = (ct << 4) + t;
        if (q < nc) {
            const int g = lst[q];
            const int h1p = colH1[t];
            const bool hasHit = (h1p != IMAX);     // exists p<q with sim>=THR (same cat)
            hit1[g] = hasHit ? lst[h1p] : g;
            hit2[g] = hasHit ? 0 : IMAX;           // keep <=> hit2 == IMAX
            float* cats  = out + (size_t)NROWS * DDIM;
            float* scso  = cats + NROWS;
            float* keepo = scso + NROWS;
            cats[g]  = hasHit ? -1.0f : (float)c;
            scso[g]  = hasHit ? 0.0f : sc[g];
            keepo[g] = hasHit ? 0.0f : 1.0f;
            if (hasHit) mergeList[atomicAdd(mergeCnt, 1)] = g;
        }
    }
}

// ---- D3: fused rows only (fp32 mean of merged originals) — 1 row/wave ----
__global__ __launch_bounds__(256) void k_out(const float* __restrict__ kin,
                                             const int* __restrict__ hit1,
                                             const int* __restrict__ hit2,
                                             const int* __restrict__ mergeCnt,
                                             const int* __restrict__ mergeList,
                                             float* __restrict__ out) {
    const int t = threadIdx.x, l = t & 63;
    const int i = (int)(blockIdx.x << 2) + (t >> 6);
    const bool keep = (hit2[i] == IMAX);

    float ax = 0.f, ay = 0.f, az = 0.f, aw = 0.f;
    if (keep) {
        // keep[i] => hit1[i] == i (diagonal is the sole first hit)
        const float4 v = ((const float4*)(kin + (size_t)i * DDIM))[l];
        ax = v.x; ay = v.y; az = v.z; aw = v.w;
        int cnt = 1;
        const int mc = *mergeCnt;
        for (int q = 0; q < mc; q++) {
            const int jr = mergeList[q];
            if (hit1[jr] == i) {
                const float4 b = ((const float4*)(kin + (size_t)jr * DDIM))[l];
                ax += b.x; ay += b.y; az += b.z; aw += b.w; cnt++;
            }
        }
        const float fc = (float)cnt;
        ax /= fc; ay /= fc; az /= fc; aw /= fc;
    }
    float4 o4; o4.x = ax; o4.y = ay; o4.z = az; o4.w = aw;
    ((float4*)(out + (size_t)i * DDIM))[l] = o4;
}

extern "C" void kernel_launch(void* const* d_in, const int* in_sizes, int n_in,
                              void* d_out, int out_size, void* d_ws, size_t ws_size,
                              hipStream_t stream) {
    (void)in_sizes; (void)n_in; (void)out_size; (void)ws_size;
    const float* kin = (const float*)d_in[0];   // kernels fp32 [N*D]
    const int*   cat = (const int*)d_in[1];     // categories int32 [N]
    const float* sc  = (const float*)d_in[2];   // scores fp32 [N]
    float* out = (float*)d_out;                 // fp32 concat: fused|cats|scores|keep

    char* ws = (char*)d_ws;
    u16* anorm      = (u16*)ws;                                 // 4 MB bf16 normalized rows
    int* hit1       = (int*)(ws + (size_t)NROWS * DDIM * 2);
    int* hit2       = hit1 + NROWS;
    int* sortedRows = hit2 + NROWS;
    int* catBase    = sortedRows + NROWS;        // 81 + pad
    int* mergeCnt   = catBase + 128;
    int* mergeList  = mergeCnt + 16;

    k_norm_sort<<<NROWS / 4 + 1, 256, 0, stream>>>(kin, cat, anorm, sortedRows,
                                                   catBase, mergeCnt);
    k_hits_cat<<<NCAT * MAXT, 256, 0, stream>>>(anorm, sc, sortedRows, catBase,
                                                hit1, hit2, mergeCnt, mergeList, out);
    k_out<<<NROWS / 4, 256, 0, stream>>>(kin, hit1, hit2, mergeCnt, mergeList, out);
}